// Round 7
// baseline (355.402 us; speedup 1.0000x reference)
//
#include <hip/hip_runtime.h>

// LSTM B=8192, T=168, P=16, H=24, gates [i,f,g,o].
// Round-7: r6 MFMA structure + TWO independent 16-batch groups per wave.
//  - r6 post-mortem: 2300 cyc/step, only ~550 issue (VALUBusy 24%) -> ~1750
//    stall (LDS round trip + MFMA/AGPR hazards + nonlin chains), 1 wave/SIMD
//    and a hard 512-wave parallelism cap (B/16). Interleaving a second
//    independent chain in the same wave fills the stalls; A-frags + biases
//    are shared (same weights), so only state/accums duplicate.
//  - x-side MFMAs issued before the h-dependent reads (off critical chain).
//  - quad<2 divergence -> zero-block pointer select (no exec-mask dance).
//  - hpad rows padded to 40 halves (80 B stride) to spread banks.
//  - 256 blocks x 64 threads (1 wave, 32 batches); x staged f16 in 4 chunks
//    of 42 steps; weight stage overwritten by x staging = natural pin.

#define T_STEPS 168
#define P_FEAT  16
#define H_SZ    24
#define TCH     42    // t-chunk length (4 chunks)
#define NB      32    // batches per wave (2 groups of 16)

typedef _Float16 half8 __attribute__((ext_vector_type(8)));
typedef _Float16 h2    __attribute__((ext_vector_type(2)));
typedef float    f32x4 __attribute__((ext_vector_type(4)));

__device__ __forceinline__ float rcp_fast(float x) {
#if __has_builtin(__builtin_amdgcn_rcpf)
    return __builtin_amdgcn_rcpf(x);
#else
    return 1.0f / x;
#endif
}
__device__ __forceinline__ float exp2_fast(float x) {
#if __has_builtin(__builtin_amdgcn_exp2f)
    return __builtin_amdgcn_exp2f(x);
#else
    return exp2f(x);
#endif
}
__device__ __forceinline__ float sigmoid_f(float x) {
    return rcp_fast(1.0f + exp2_fast(x * -1.44269504f));
}
__device__ __forceinline__ float tanh_f(float x) {
    return 1.0f - 2.0f * rcp_fast(1.0f + exp2_fast(x * 2.88539008f));
}
__device__ __forceinline__ h2 pack2(float a, float b) {
    h2 r; r.x = (_Float16)a; r.y = (_Float16)b; return r;
}

__global__ __launch_bounds__(64, 1) void lstm_mfma2(
    const float* __restrict__ x,
    const float* __restrict__ W_ih,
    const float* __restrict__ W_hh,
    const float* __restrict__ b_ih,
    const float* __restrict__ b_hh,
    const float* __restrict__ W_lin,
    const float* __restrict__ b_lin,
    float* __restrict__ out)
{
    __shared__ __align__(16) _Float16 xs16[NB][TCH][16];  // 43008 B
    __shared__ __align__(16) _Float16 hpad[NB][40];       //  2560 B: h[24]+16 pad(0)
    __shared__ __align__(16) _Float16 zblk[16];           //    32 B zeros (B2 pad)
    __shared__ __align__(16) float    thbuf[NB][24];      //  3072 B (epilogue)

    const int lane = threadIdx.x;   // one wave per block
    const int n    = lane & 15;     // batch column within group
    const int quad = lane >> 4;     // 0..3

    // ---- one-time: stage fused W (f32) into xs16 space ----
    float* wstage = reinterpret_cast<float*>(&xs16[0][0][0]);  // 96*40 f32
    for (int idx = lane; idx < 96 * 40; idx += 64) {
        const int j = idx / 40;
        const int k = idx - j * 40;
        wstage[idx] = (k < 24) ? W_hh[j * 24 + k] : W_ih[j * 16 + (k - 24)];
    }
    __builtin_amdgcn_wave_barrier();

    // ---- A-fragments (permuted rows: position p = gate p%4 of unit (p/4)*6+mt)
    // A-frag lane layout [m120]: row m = lane&15, k = quad*8+j.
    half8 A1[6], A2[6];
    f32x4 biasf[6];
    #pragma unroll
    for (int mt = 0; mt < 6; mt++) {
        const int grow = (n & 3) * 24 + (n >> 2) * 6 + mt;
        #pragma unroll
        for (int j = 0; j < 8; j++) {
            const int k = quad * 8 + j;
            A1[mt][j] = (k < 24) ? (_Float16)wstage[grow * 40 + k] : (_Float16)0.0f;
            A2[mt][j] = (k < 16) ? (_Float16)wstage[grow * 40 + 24 + k] : (_Float16)0.0f;
        }
        #pragma unroll
        for (int r = 0; r < 4; r++) {
            const int row = r * 24 + quad * 6 + mt;
            biasf[mt][r] = b_ih[row] + b_hh[row];
        }
    }
    __builtin_amdgcn_wave_barrier();   // wstage dead; x staging reuses the space

    // ---- zero hpad (incl. pad halves, never written again) + zblk ----
    {
        unsigned* hz = reinterpret_cast<unsigned*>(&hpad[0][0]);   // 640 dwords
        for (int i = lane; i < 640; i += 64) hz[i] = 0u;
        if (lane < 8) reinterpret_cast<unsigned*>(zblk)[lane] = 0u;
    }
    __builtin_amdgcn_wave_barrier();

    float cA[6] = {0, 0, 0, 0, 0, 0}, cB[6] = {0, 0, 0, 0, 0, 0};
    float hA[6], hB[6];

    const float4* xsrc = reinterpret_cast<const float4*>(x)
                       + (size_t)(blockIdx.x * NB) * (T_STEPS * P_FEAT / 4);

    // B2 source: quads 0..1 read x halves, quads 2..3 read the zero block
    const _Float16* xrowbaseA = (quad < 2) ? &xs16[n][0][quad * 8]      : zblk;
    const _Float16* xrowbaseB = (quad < 2) ? &xs16[16 + n][0][quad * 8] : zblk;
    const int xstep = (quad < 2) ? 16 : 0;   // halves per t for the selected base

    for (int ch = 0; ch < 4; ch++) {
        // stage NB batches x TCH steps x 16 f32 -> f16 (5376 float4, 84/lane)
        for (int i = 0; i < TCH * 2; i++) {
            const int m   = lane + 64 * i;      // 0..5375
            const int b   = m / 168;            // 168 float4 per batch-chunk
            const int rem = m - b * 168;
            const float4 v = xsrc[(size_t)b * (T_STEPS * P_FEAT / 4) + ch * 168 + rem];
            h2* dst = reinterpret_cast<h2*>(&xs16[0][0][0]) + b * 336 + rem * 2;
            dst[0] = pack2(v.x, v.y);
            dst[1] = pack2(v.z, v.w);
        }
        __builtin_amdgcn_wave_barrier();

        for (int t = 0; t < TCH; t++) {
            // ---- x-side first (independent of h) ----
            const half8 B2A = *reinterpret_cast<const half8*>(xrowbaseA + t * xstep);
            const half8 B2B = *reinterpret_cast<const half8*>(xrowbaseB + t * xstep);
            f32x4 gA[6], gB[6];
            #pragma unroll
            for (int mt = 0; mt < 6; mt++) {
                gA[mt] = __builtin_amdgcn_mfma_f32_16x16x32_f16(A2[mt], B2A, biasf[mt], 0, 0, 0);
                gB[mt] = __builtin_amdgcn_mfma_f32_16x16x32_f16(A2[mt], B2B, biasf[mt], 0, 0, 0);
            }

            // ---- h-side (chain head: reads follow last step's writes) ----
            const half8 B1A = *reinterpret_cast<const half8*>(&hpad[n][quad * 8]);
            const half8 B1B = *reinterpret_cast<const half8*>(&hpad[16 + n][quad * 8]);
            #pragma unroll
            for (int mt = 0; mt < 6; mt++) {
                gA[mt] = __builtin_amdgcn_mfma_f32_16x16x32_f16(A1[mt], B1A, gA[mt], 0, 0, 0);
                gB[mt] = __builtin_amdgcn_mfma_f32_16x16x32_f16(A1[mt], B1B, gB[mt], 0, 0, 0);
            }

            // ---- nonlinearities: two independent chains, compiler interleaves
            #pragma unroll
            for (int mt = 0; mt < 6; mt++) {
                const float igA = sigmoid_f(gA[mt][0]);
                const float fgA = sigmoid_f(gA[mt][1]);
                const float ggA = tanh_f   (gA[mt][2]);
                const float ogA = sigmoid_f(gA[mt][3]);
                cA[mt] = fgA * cA[mt] + igA * ggA;
                hA[mt] = ogA * tanh_f(cA[mt]);

                const float igB = sigmoid_f(gB[mt][0]);
                const float fgB = sigmoid_f(gB[mt][1]);
                const float ggB = tanh_f   (gB[mt][2]);
                const float ogB = sigmoid_f(gB[mt][3]);
                cB[mt] = fgB * cB[mt] + igB * ggB;
                hB[mt] = ogB * tanh_f(cB[mt]);
            }

            // ---- write h for both groups (lane owns units quad*6..quad*6+5)
            *reinterpret_cast<h2*>(&hpad[n][quad * 6 + 0])      = pack2(hA[0], hA[1]);
            *reinterpret_cast<h2*>(&hpad[n][quad * 6 + 2])      = pack2(hA[2], hA[3]);
            *reinterpret_cast<h2*>(&hpad[n][quad * 6 + 4])      = pack2(hA[4], hA[5]);
            *reinterpret_cast<h2*>(&hpad[16 + n][quad * 6 + 0]) = pack2(hB[0], hB[1]);
            *reinterpret_cast<h2*>(&hpad[16 + n][quad * 6 + 2]) = pack2(hB[2], hB[3]);
            *reinterpret_cast<h2*>(&hpad[16 + n][quad * 6 + 4]) = pack2(hB[4], hB[5]);
            __builtin_amdgcn_wave_barrier();
        }
        __builtin_amdgcn_wave_barrier();   // xs16 rewrite next chunk
    }

    // ---- epilogue: out[b][j] = b_lin[j] + sum_k tanh(h[k]) * W_lin[j][k] ----
    #pragma unroll
    for (int s = 0; s < 6; s++) {
        thbuf[n][quad * 6 + s]      = tanh_f(hA[s]);
        thbuf[16 + n][quad * 6 + s] = tanh_f(hB[s]);
    }
    __builtin_amdgcn_wave_barrier();

    #pragma unroll
    for (int grp = 0; grp < 2; grp++) {
        const int bb = grp * 16 + n;
        float th[24];
        #pragma unroll
        for (int kk = 0; kk < 6; kk++) {
            const f32x4 t4 = *reinterpret_cast<const f32x4*>(&thbuf[bb][4 * kk]);
            th[4 * kk + 0] = t4[0]; th[4 * kk + 1] = t4[1];
            th[4 * kk + 2] = t4[2]; th[4 * kk + 3] = t4[3];
        }
        const int batch = blockIdx.x * NB + bb;
        #pragma unroll
        for (int s = 0; s < 6; s++) {
            const int j = quad * 6 + s;
            const float* wl = &W_lin[j * 24];
            float acc = b_lin[j];
            #pragma unroll
            for (int k = 0; k < 24; k++) acc = fmaf(th[k], wl[k], acc);
            out[(size_t)batch * 24 + j] = acc;
        }
    }
}

extern "C" void kernel_launch(void* const* d_in, const int* in_sizes, int n_in,
                              void* d_out, int out_size, void* d_ws, size_t ws_size,
                              hipStream_t stream) {
    const float* x     = (const float*)d_in[0];
    const float* W_ih  = (const float*)d_in[1];
    const float* W_hh  = (const float*)d_in[2];
    const float* b_ih  = (const float*)d_in[3];
    const float* b_hh  = (const float*)d_in[4];
    const float* W_lin = (const float*)d_in[5];
    const float* b_lin = (const float*)d_in[6];
    float* out = (float*)d_out;

    const int B = in_sizes[0] / (T_STEPS * P_FEAT);   // 8192
    dim3 grid(B / NB), block(64);                     // 256 waves, 32 batches each
    lstm_mfma2<<<grid, block, 0, stream>>>(x, W_ih, W_hh, b_ih, b_hh, W_lin, b_lin, out);
}

// Round 8
// 234.194 us; speedup vs baseline: 1.5176x; 1.5176x over previous
//
#include <hip/hip_runtime.h>

// LSTM B=8192, T=168, P=16, H=24, gates [i,f,g,o].
// Round-8: split each 16-batch chain across TWO waves (one block), halving
// per-wave issue (30 trans, 3+3 MFMA per step) and filling all 1024 SIMDs.
//  - r7 lesson: 512 chains is a hard cap; doubling per-wave work regressed
//    (in-order issue, trans-issue floor). So divide the step, don't multiply.
//  - Ping-pong hpad: write buf 1-p, read buf p -> ONE __syncthreads per step.
//  - x-side MFMA pipelined one step ahead (gx(t+1) during step t's nonlin);
//    h-critical path is a single MFMA.
//  - 512 blocks x 128 threads; 2 blocks/CU; x staged f16 in 2 chunks of 84.

#define T_STEPS 168
#define P_FEAT  16
#define H_SZ    24
#define TCH     84    // t-chunk length (2 chunks)
#define NB      16    // batches per block

typedef _Float16 half8 __attribute__((ext_vector_type(8)));
typedef _Float16 h2    __attribute__((ext_vector_type(2)));
typedef float    f32x4 __attribute__((ext_vector_type(4)));

__device__ __forceinline__ float rcp_fast(float x) {
#if __has_builtin(__builtin_amdgcn_rcpf)
    return __builtin_amdgcn_rcpf(x);
#else
    return 1.0f / x;
#endif
}
__device__ __forceinline__ float exp2_fast(float x) {
#if __has_builtin(__builtin_amdgcn_exp2f)
    return __builtin_amdgcn_exp2f(x);
#else
    return exp2f(x);
#endif
}
__device__ __forceinline__ float sigmoid_f(float x) {
    return rcp_fast(1.0f + exp2_fast(x * -1.44269504f));
}
__device__ __forceinline__ float tanh_f(float x) {
    return 1.0f - 2.0f * rcp_fast(1.0f + exp2_fast(x * 2.88539008f));
}
__device__ __forceinline__ h2 pack2(float a, float b) {
    h2 r; r.x = (_Float16)a; r.y = (_Float16)b; return r;
}

__global__ __launch_bounds__(128, 1) void lstm_sp(
    const float* __restrict__ x,
    const float* __restrict__ W_ih,
    const float* __restrict__ W_hh,
    const float* __restrict__ b_ih,
    const float* __restrict__ b_hh,
    const float* __restrict__ W_lin,
    const float* __restrict__ b_lin,
    float* __restrict__ out)
{
    __shared__ __align__(16) _Float16 xs16[NB][TCH][16];   // 43008 B
    __shared__ __align__(16) _Float16 hpad[2][NB][40];     //  5120 B ping-pong
    __shared__ __align__(16) _Float16 zblk[16];            //    32 B zeros
    __shared__ __align__(16) float    thbuf[NB][24];       //  1536 B

    const int tid  = threadIdx.x;
    const int w    = tid >> 6;       // wave 0/1: m-tiles {3w..3w+2}
    const int lane = tid & 63;
    const int n    = lane & 15;      // batch column
    const int quad = lane >> 4;      // 0..3

    // ---- one-time: stage fused W (f32) into xs16 space ----
    float* wstage = reinterpret_cast<float*>(&xs16[0][0][0]);  // 96*40 f32
    for (int idx = tid; idx < 96 * 40; idx += 128) {
        const int j = idx / 40;
        const int k = idx - j * 40;
        wstage[idx] = (k < 24) ? W_hh[j * 24 + k] : W_ih[j * 16 + (k - 24)];
    }
    __syncthreads();

    // ---- A-fragments for this wave's 3 m-tiles ----
    // permuted rows: tile position p = gate p%4 of unit (p/4)*6+mt.
    // A-frag [m120]: row m = lane&15, k = quad*8+j.
    half8 A1[3], A2[3];
    f32x4 biasf[3];
    #pragma unroll
    for (int s = 0; s < 3; s++) {
        const int mt   = w * 3 + s;
        const int grow = (n & 3) * 24 + (n >> 2) * 6 + mt;
        #pragma unroll
        for (int j = 0; j < 8; j++) {
            const int k = quad * 8 + j;
            A1[s][j] = (k < 24) ? (_Float16)wstage[grow * 40 + k] : (_Float16)0.0f;
            A2[s][j] = (k < 16) ? (_Float16)wstage[grow * 40 + 24 + k] : (_Float16)0.0f;
        }
        #pragma unroll
        for (int r = 0; r < 4; r++) {
            const int row = r * 24 + quad * 6 + mt;
            biasf[s][r] = b_ih[row] + b_hh[row];
        }
    }
    __syncthreads();   // wstage dead; x staging reuses the space

    // ---- zero both hpad buffers (pad halves stay 0 forever) + zblk ----
    {
        unsigned* hz = reinterpret_cast<unsigned*>(&hpad[0][0][0]);  // 640 dwords
        for (int i = tid; i < 640; i += 128) hz[i] = 0u;
        if (tid < 8) reinterpret_cast<unsigned*>(zblk)[tid] = 0u;
    }
    __syncthreads();

    float c[3] = {0, 0, 0};
    float hv[3] = {0, 0, 0};

    const float4* xsrc = reinterpret_cast<const float4*>(x)
                       + (size_t)(blockIdx.x * NB) * (T_STEPS * P_FEAT / 4);

    // B2 source: quads 0..1 read x halves, quads 2..3 the zero block
    const _Float16* xrowbase = (quad < 2) ? &xs16[n][0][quad * 8] : zblk;
    const int xstep = (quad < 2) ? 16 : 0;

    int bufp = 0;
    for (int ch = 0; ch < 2; ch++) {
        // stage NB x TCH x 16 f32 -> f16: 5376 float4, 42 per thread
        for (int i = 0; i < 42; i++) {
            const int m   = tid + 128 * i;      // 0..5375
            const int b   = m / 336;            // 336 float4 per batch-chunk
            const int rem = m - b * 336;
            const float4 v = xsrc[(size_t)b * (T_STEPS * P_FEAT / 4) + ch * 336 + rem];
            h2* dst = reinterpret_cast<h2*>(&xs16[0][0][0]) + b * 672 + rem * 2;
            dst[0] = pack2(v.x, v.y);
            dst[1] = pack2(v.z, v.w);
        }
        __syncthreads();

        // gx prologue for t=0 of this chunk
        f32x4 gx[3];
        {
            const half8 B2 = *reinterpret_cast<const half8*>(xrowbase);
            #pragma unroll
            for (int s = 0; s < 3; s++)
                gx[s] = __builtin_amdgcn_mfma_f32_16x16x32_f16(A2[s], B2, biasf[s], 0, 0, 0);
        }

        for (int t = 0; t < TCH; t++) {
            // h-read (chain head) — issue first so MFMA can start ASAP
            const half8 B1 = *reinterpret_cast<const half8*>(&hpad[bufp][n][quad * 8]);
            // next step's x fragment (last iter: index 0, result discarded)
            const int  tn  = (t + 1 < TCH) ? t + 1 : 0;
            const half8 B2n = *reinterpret_cast<const half8*>(xrowbase + tn * xstep);

            f32x4 g[3];
            #pragma unroll
            for (int s = 0; s < 3; s++)
                g[s] = __builtin_amdgcn_mfma_f32_16x16x32_f16(A1[s], B1, gx[s], 0, 0, 0);

            // independent: next step's x-side MFMAs fill the nonlin stall
            #pragma unroll
            for (int s = 0; s < 3; s++)
                gx[s] = __builtin_amdgcn_mfma_f32_16x16x32_f16(A2[s], B2n, biasf[s], 0, 0, 0);

            // nonlinearities for own 3 units (gate r = g[s][r])
            #pragma unroll
            for (int s = 0; s < 3; s++) {
                const float ig = sigmoid_f(g[s][0]);
                const float fg = sigmoid_f(g[s][1]);
                const float gg = tanh_f   (g[s][2]);
                const float og = sigmoid_f(g[s][3]);
                c[s]  = fg * c[s] + ig * gg;
                hv[s] = og * tanh_f(c[s]);
            }

            // write own 3 units to the OTHER buffer
            const int u0 = quad * 6 + w * 3;
            hpad[1 - bufp][n][u0 + 0] = (_Float16)hv[0];
            hpad[1 - bufp][n][u0 + 1] = (_Float16)hv[1];
            hpad[1 - bufp][n][u0 + 2] = (_Float16)hv[2];

            bufp ^= 1;
            __syncthreads();   // writes visible before next step's reads
        }
    }

    // ---- epilogue: out[b][j] = b_lin[j] + sum_k tanh(h[k]) * W_lin[j][k] ----
    {
        const int u0 = quad * 6 + w * 3;
        #pragma unroll
        for (int s = 0; s < 3; s++) thbuf[n][u0 + s] = tanh_f(hv[s]);
    }
    __syncthreads();

    float th[24];
    #pragma unroll
    for (int kk = 0; kk < 6; kk++) {
        const f32x4 t4 = *reinterpret_cast<const f32x4*>(&thbuf[n][4 * kk]);
        th[4 * kk + 0] = t4[0]; th[4 * kk + 1] = t4[1];
        th[4 * kk + 2] = t4[2]; th[4 * kk + 3] = t4[3];
    }
    const int batch = blockIdx.x * NB + n;
    #pragma unroll
    for (int s = 0; s < 3; s++) {
        const int j = quad * 6 + w * 3 + s;
        const float* wl = &W_lin[j * 24];
        float acc = b_lin[j];
        #pragma unroll
        for (int k = 0; k < 24; k++) acc = fmaf(th[k], wl[k], acc);
        out[(size_t)batch * 24 + j] = acc;
    }
}

extern "C" void kernel_launch(void* const* d_in, const int* in_sizes, int n_in,
                              void* d_out, int out_size, void* d_ws, size_t ws_size,
                              hipStream_t stream) {
    const float* x     = (const float*)d_in[0];
    const float* W_ih  = (const float*)d_in[1];
    const float* W_hh  = (const float*)d_in[2];
    const float* b_ih  = (const float*)d_in[3];
    const float* b_hh  = (const float*)d_in[4];
    const float* W_lin = (const float*)d_in[5];
    const float* b_lin = (const float*)d_in[6];
    float* out = (float*)d_out;

    const int B = in_sizes[0] / (T_STEPS * P_FEAT);   // 8192
    dim3 grid(B / NB), block(128);                    // 512 blocks x 2 waves
    lstm_sp<<<grid, block, 0, stream>>>(x, W_ih, W_hh, b_ih, b_hh, W_lin, b_lin, out);
}

// Round 9
// 203.199 us; speedup vs baseline: 1.7490x; 1.1525x over previous
//
#include <hip/hip_runtime.h>

// LSTM B=8192, T=168, P=16, H=24, gates [i,f,g,o].
// Round-9: trans-pipe spreading + self-aligned 8-tile MFMA layout.
//  - Cost model fitting r5-r8: wave64 transcendental ~16 cyc issue; exp+rcp
//    per activation -> per-wave trans streams were the floor (r6 120 instr
//    *16 = 1920 ~ measured 2300; r7 3840 ~ 3600; r8 960+sync ~ 1900).
//  - Fix A: 8-tile permutation (tile mt row p = gate p%4 of unit 8*(p/4)+mt,
//    rows 12..15 zero): lane (q,n) outputs units (8q+2w, 8q+2w+1) == the
//    K-positions of its own B1 dword w -> h-exchange = 1 ds_write_b32 +
//    1 ds_read_b128 (dword i comes from wave i), zero shuffle arithmetic.
//  - Fix B: 4 waves/block share one 16-batch chain (wave w = tiles 2w,2w+1,
//    2 units/lane, 20 trans instr/step); 512 blocks x 256 thr = 2048 waves
//    = 2/SIMD on all 256 CUs. Ping-pong hx, ONE __syncthreads/step.
//  - x-side MFMA pipelined one step ahead (independent of h).

#define T_STEPS 168
#define P_FEAT  16
#define H_SZ    24
#define TCH     84    // t-chunk length (2 chunks)
#define NB      16    // batches per block

typedef _Float16 half8 __attribute__((ext_vector_type(8)));
typedef _Float16 h2    __attribute__((ext_vector_type(2)));
typedef float    f32x4 __attribute__((ext_vector_type(4)));

__device__ __forceinline__ float rcp_fast(float x) {
#if __has_builtin(__builtin_amdgcn_rcpf)
    return __builtin_amdgcn_rcpf(x);
#else
    return 1.0f / x;
#endif
}
__device__ __forceinline__ float exp2_fast(float x) {
#if __has_builtin(__builtin_amdgcn_exp2f)
    return __builtin_amdgcn_exp2f(x);
#else
    return exp2f(x);
#endif
}
__device__ __forceinline__ float sigmoid_f(float x) {
    return rcp_fast(1.0f + exp2_fast(x * -1.44269504f));
}
__device__ __forceinline__ float tanh_f(float x) {
    return 1.0f - 2.0f * rcp_fast(1.0f + exp2_fast(x * 2.88539008f));
}
__device__ __forceinline__ h2 pack2(float a, float b) {
    h2 r; r.x = (_Float16)a; r.y = (_Float16)b; return r;
}

__global__ __launch_bounds__(256, 2) void lstm_4w(
    const float* __restrict__ x,
    const float* __restrict__ W_ih,
    const float* __restrict__ W_hh,
    const float* __restrict__ b_ih,
    const float* __restrict__ b_hh,
    const float* __restrict__ W_lin,
    const float* __restrict__ b_lin,
    float* __restrict__ out)
{
    __shared__ __align__(16) _Float16 xs16[NB][TCH][16];  // 43008 B (W-stage reused)
    __shared__ __align__(16) h2       hx[2][4][NB][4];    //  2048 B ping-pong h state
    __shared__ __align__(16) h2       zblk[8];            //    32 B zeros (B2 pad)
    __shared__ __align__(16) float    thbuf[NB][24];      //  1536 B epilogue

    const int tid  = threadIdx.x;
    const int w    = tid >> 6;       // wave 0..3: tiles {2w, 2w+1}
    const int lane = tid & 63;
    const int n    = lane & 15;      // batch col (B/C) == row p supplied (A)
    const int q    = lane >> 4;      // k-chunk (A/B) == output quad (C)

    // ---- one-time: stage fused W (f32) into xs16 space ----
    float* wstage = reinterpret_cast<float*>(&xs16[0][0][0]);  // 96*40 f32
    for (int idx = tid; idx < 96 * 40; idx += 256) {
        const int j = idx / 40;
        const int k = idx - j * 40;
        wstage[idx] = (k < 24) ? W_hh[j * 24 + k] : W_ih[j * 16 + (k - 24)];
    }
    __syncthreads();

    // ---- A-fragments for this wave's 2 tiles (mt = 2w+s) ----
    // row p (= lane&15): gate p%4 of unit 8*(p/4)+mt; rows p>=12 are zero.
    // A-frag layout [m120]: A[m=lane&15][k=quad*8+j].
    half8 A1[2], A2[2];
    f32x4 biasf[2];
    #pragma unroll
    for (int s = 0; s < 2; s++) {
        const int mt = 2 * w + s;
        const int p  = n;
        const bool vrow = (p < 12);
        const int grow = vrow ? ((p & 3) * 24 + 8 * (p >> 2) + mt) : 0;
        #pragma unroll
        for (int j = 0; j < 8; j++) {
            const int k = q * 8 + j;
            A1[s][j] = (vrow && k < 24) ? (_Float16)wstage[grow * 40 + k]      : (_Float16)0.0f;
            A2[s][j] = (vrow && k < 16) ? (_Float16)wstage[grow * 40 + 24 + k] : (_Float16)0.0f;
        }
        #pragma unroll
        for (int r = 0; r < 4; r++) {
            // lane (q,n) receives gates r of unit u = 8q+mt (valid for q<3)
            const int u = 8 * q + mt;
            biasf[s][r] = (q < 3) ? (b_ih[r * 24 + u] + b_hh[r * 24 + u]) : 0.0f;
        }
    }
    __syncthreads();   // wstage dead; x staging reuses the space

    // ---- zero hx (both buffers, incl. q=3 rows: stay 0 forever) + zblk ----
    {
        unsigned* hz = reinterpret_cast<unsigned*>(&hx[0][0][0][0]);   // 512 dwords
        for (int i = tid; i < 512; i += 256) hz[i] = 0u;
        if (tid < 8) reinterpret_cast<unsigned*>(zblk)[tid] = 0u;
    }
    __syncthreads();

    float c[2] = {0.0f, 0.0f};
    float hv[2] = {0.0f, 0.0f};

    const float4* xsrc = reinterpret_cast<const float4*>(x)
                       + (size_t)(blockIdx.x * NB) * (T_STEPS * P_FEAT / 4);

    // B2 source: quads 0..1 read x halves, quads 2..3 the zero block
    const _Float16* xrowbase = (q < 2) ? &xs16[n][0][q * 8]
                                       : reinterpret_cast<const _Float16*>(zblk);
    const int xstep = (q < 2) ? 16 : 0;

    int bufp = 0;
    for (int ch = 0; ch < 2; ch++) {
        // stage NB x TCH x 16 f32 -> f16: 5376 float4, 21 per thread
        for (int i = 0; i < 21; i++) {
            const int m   = tid + 256 * i;      // 0..5375
            const int b   = m / 336;            // 336 float4 per batch-chunk
            const int rem = m - b * 336;
            const float4 v = xsrc[(size_t)b * 672 + ch * 336 + rem];
            h2* dst = reinterpret_cast<h2*>(&xs16[0][0][0]) + b * 672 + rem * 2;
            dst[0] = pack2(v.x, v.y);
            dst[1] = pack2(v.z, v.w);
        }
        __syncthreads();

        // gx prologue for t=0 of this chunk
        f32x4 gx[2];
        {
            const half8 B2 = *reinterpret_cast<const half8*>(xrowbase);
            #pragma unroll
            for (int s = 0; s < 2; s++)
                gx[s] = __builtin_amdgcn_mfma_f32_16x16x32_f16(A2[s], B2, biasf[s], 0, 0, 0);
        }

        for (int t = 0; t < TCH; t++) {
            // B1: dword i = units (8q+2i, 8q+2i+1) = wave i's pair for (q,n)
            const half8 B1 = *reinterpret_cast<const half8*>(&hx[bufp][q][n][0]);
            // prefetch next step's x fragment (last iter: dummy index 0)
            const int tn = (t + 1 < TCH) ? t + 1 : 0;
            const half8 B2n = *reinterpret_cast<const half8*>(xrowbase + tn * xstep);

            f32x4 g[2];
            #pragma unroll
            for (int s = 0; s < 2; s++)
                g[s] = __builtin_amdgcn_mfma_f32_16x16x32_f16(A1[s], B1, gx[s], 0, 0, 0);
            #pragma unroll
            for (int s = 0; s < 2; s++)
                gx[s] = __builtin_amdgcn_mfma_f32_16x16x32_f16(A2[s], B2n, biasf[s], 0, 0, 0);

            // nonlinearities: 2 units (q<3 meaningful), 20 trans instr total
            #pragma unroll
            for (int s = 0; s < 2; s++) {
                const float ig = sigmoid_f(g[s][0]);
                const float fg = sigmoid_f(g[s][1]);
                const float gg = tanh_f   (g[s][2]);
                const float og = sigmoid_f(g[s][3]);
                c[s]  = fg * c[s] + ig * gg;
                hv[s] = og * tanh_f(c[s]);
            }

            // publish own pair to the other buffer; q=3 has nothing to write
            if (q < 3) hx[1 - bufp][q][n][w] = pack2(hv[0], hv[1]);
            bufp ^= 1;
            __syncthreads();
        }
    }

    // ---- epilogue: out[b][u] = b_lin[u] + sum_k tanh(h[k]) * W_lin[u][k] ----
    if (q < 3) {
        thbuf[n][8 * q + 2 * w + 0] = tanh_f(hv[0]);
        thbuf[n][8 * q + 2 * w + 1] = tanh_f(hv[1]);
    }
    __syncthreads();

    if (q < 3) {
        const int batch = blockIdx.x * NB + n;
        #pragma unroll
        for (int s = 0; s < 2; s++) {
            const int u = 8 * q + 2 * w + s;
            const float* wl = &W_lin[u * 24];
            float acc = b_lin[u];
            #pragma unroll
            for (int k = 0; k < 24; k++) acc = fmaf(thbuf[n][k], wl[k], acc);
            out[(size_t)batch * 24 + u] = acc;
        }
    }
}

extern "C" void kernel_launch(void* const* d_in, const int* in_sizes, int n_in,
                              void* d_out, int out_size, void* d_ws, size_t ws_size,
                              hipStream_t stream) {
    const float* x     = (const float*)d_in[0];
    const float* W_ih  = (const float*)d_in[1];
    const float* W_hh  = (const float*)d_in[2];
    const float* b_ih  = (const float*)d_in[3];
    const float* b_hh  = (const float*)d_in[4];
    const float* W_lin = (const float*)d_in[5];
    const float* b_lin = (const float*)d_in[6];
    float* out = (float*)d_out;

    const int B = in_sizes[0] / (T_STEPS * P_FEAT);   // 8192
    dim3 grid(B / NB), block(256);                    // 512 blocks x 4 waves
    lstm_4w<<<grid, block, 0, stream>>>(x, W_ih, W_hh, b_ih, b_hh, W_lin, b_lin, out);
}